// Round 4
// baseline (458.680 us; speedup 1.0000x reference)
//
#include <hip/hip_runtime.h>

#define D 128   // feature dim
#define H 64    // hidden dim of classifier

// ---------- bf16 helpers (bit-level, RNE) ----------

__device__ __forceinline__ unsigned int bf16_rne(float f) {
    unsigned int u = __float_as_uint(f);
    u += 0x7fffu + ((u >> 16) & 1u);
    return u >> 16;
}
__device__ __forceinline__ unsigned int pack_bf16(float a, float b) {
    return bf16_rne(a) | (bf16_rne(b) << 16);
}
__device__ __forceinline__ float bf16_lo(unsigned int u) { return __uint_as_float(u << 16); }
__device__ __forceinline__ float bf16_hi(unsigned int u) { return __uint_as_float(u & 0xffff0000u); }

// ---------- CSR construction ----------

static __global__ void hist_k(const int* __restrict__ ei, int E, int* __restrict__ cnt) {
    int e = blockIdx.x * blockDim.x + threadIdx.x;
    if (e < E) atomicAdd(&cnt[ei[E + e]], 1);   // dst row of edge_index
}

static __global__ void dinv_k(const int* __restrict__ cnt, float* __restrict__ dinv, int n) {
    int i = blockIdx.x * blockDim.x + threadIdx.x;
    if (i < n) dinv[i] = rsqrtf((float)cnt[i] + 1.0f);   // +1 for self loop; deg >= 1 always
}

static __global__ void scanA_k(const int* __restrict__ cnt, int n, int* __restrict__ bsum) {
    __shared__ int s[256];
    int i = blockIdx.x * 256 + threadIdx.x;
    s[threadIdx.x] = (i < n) ? cnt[i] : 0;
    __syncthreads();
    for (int off = 128; off > 0; off >>= 1) {
        if ((int)threadIdx.x < off) s[threadIdx.x] += s[threadIdx.x + off];
        __syncthreads();
    }
    if (threadIdx.x == 0) bsum[blockIdx.x] = s[0];
}

static __global__ void scanB_k(int* __restrict__ bsum, int nb) {
    if (threadIdx.x == 0 && blockIdx.x == 0) {
        int run = 0;
        for (int i = 0; i < nb; i++) { int t = bsum[i]; bsum[i] = run; run += t; }
    }
}

static __global__ void scanC_k(const int* __restrict__ cnt, int n, const int* __restrict__ bsum,
                               int* __restrict__ rowptr) {
    __shared__ int s[256];
    int i = blockIdx.x * 256 + threadIdx.x;
    int v = (i < n) ? cnt[i] : 0;
    s[threadIdx.x] = v;
    __syncthreads();
    for (int off = 1; off < 256; off <<= 1) {       // inclusive Hillis-Steele
        int t = ((int)threadIdx.x >= off) ? s[threadIdx.x - off] : 0;
        __syncthreads();
        s[threadIdx.x] += t;
        __syncthreads();
    }
    if (i < n) {
        int excl = bsum[blockIdx.x] + s[threadIdx.x] - v;
        rowptr[i] = excl;
        if (i == n - 1) rowptr[n] = excl + v;
    }
}

static __global__ void cursor_init_k(const int* __restrict__ rowptr, int* __restrict__ cursor, int n) {
    int i = blockIdx.x * blockDim.x + threadIdx.x;
    if (i < n) cursor[i] = rowptr[i];
}

static __global__ void fill_k(const int* __restrict__ ei, int E,
                              int* __restrict__ cursor, int* __restrict__ csr_src) {
    int e = blockIdx.x * blockDim.x + threadIdx.x;
    if (e < E) {
        int s = ei[e];
        int d = ei[E + e];
        csr_src[atomicAdd(&cursor[d], 1)] = s;   // absolute position; order within node irrelevant
    }
}

// ---------- GEMM: hb = bf16( dinv[row] * (x @ W) ) ----------
// 64-row x 128-col tile, 256 threads, K chunked by 32. LDS 24 KB -> high occupancy.
// PACKED: input x is bf16-packed (agg output); else fp32 (layer-1 input).
// Epilogue pre-scales by dinv[row] so aggregation needs no per-edge dinv gather.

template <bool PACKED>
static __global__ __launch_bounds__(256) void gemm_k(const void* __restrict__ xin,
                                                     const float* __restrict__ W,
                                                     const float* __restrict__ dinv,
                                                     unsigned int* __restrict__ hb, int n) {
    __shared__ float Ws[32 * D];     // [kk][col] 16 KB
    __shared__ float xT[32 * 64];    // [kk][row]  8 KB
    const int tid = threadIdx.x;
    const int row0 = blockIdx.x * 64;
    const int tx = tid & 31;        // cols 4*tx .. 4*tx+3
    const int ty = tid >> 5;        // rows 8*ty .. 8*ty+7
    const int sr = tid & 63;        // staging row
    const int sk = (tid >> 6) * 4;  // staging k-offset: 0,4,8,12 (+16 for second quad)
    const int gr = row0 + sr;

    float acc[8][4];
#pragma unroll
    for (int r = 0; r < 8; r++)
#pragma unroll
        for (int c = 0; c < 4; c++) acc[r][c] = 0.f;

    for (int kc = 0; kc < D; kc += 32) {
        float4 wreg[4];
#pragma unroll
        for (int i = 0; i < 4; i++)
            wreg[i] = ((const float4*)(W + kc * D))[tid + 256 * i];
        float4 v0 = make_float4(0.f, 0.f, 0.f, 0.f), v1 = v0;
        if (gr < n) {
            if constexpr (PACKED) {
                const uint2* xp = (const uint2*)xin;
                uint2 u0 = xp[(size_t)gr * 32 + ((kc + sk) >> 2)];
                uint2 u1 = xp[(size_t)gr * 32 + ((kc + sk + 16) >> 2)];
                v0 = make_float4(bf16_lo(u0.x), bf16_hi(u0.x), bf16_lo(u0.y), bf16_hi(u0.y));
                v1 = make_float4(bf16_lo(u1.x), bf16_hi(u1.x), bf16_lo(u1.y), bf16_hi(u1.y));
            } else {
                const float* xf = (const float*)xin;
                v0 = *(const float4*)&xf[(size_t)gr * D + kc + sk];
                v1 = *(const float4*)&xf[(size_t)gr * D + kc + sk + 16];
            }
        }
        __syncthreads();   // previous chunk's compute done
#pragma unroll
        for (int i = 0; i < 4; i++)
            ((float4*)Ws)[tid + 256 * i] = wreg[i];
        xT[(sk + 0) * 64 + sr] = v0.x;
        xT[(sk + 1) * 64 + sr] = v0.y;
        xT[(sk + 2) * 64 + sr] = v0.z;
        xT[(sk + 3) * 64 + sr] = v0.w;
        xT[(sk + 16) * 64 + sr] = v1.x;
        xT[(sk + 17) * 64 + sr] = v1.y;
        xT[(sk + 18) * 64 + sr] = v1.z;
        xT[(sk + 19) * 64 + sr] = v1.w;
        __syncthreads();

#pragma unroll 8
        for (int k = 0; k < 32; k++) {
            float4 w  = *(const float4*)&Ws[k * D + tx * 4];
            float4 xa = *(const float4*)&xT[k * 64 + ty * 8];
            float4 xb = *(const float4*)&xT[k * 64 + ty * 8 + 4];
            acc[0][0] = fmaf(xa.x, w.x, acc[0][0]); acc[0][1] = fmaf(xa.x, w.y, acc[0][1]);
            acc[0][2] = fmaf(xa.x, w.z, acc[0][2]); acc[0][3] = fmaf(xa.x, w.w, acc[0][3]);
            acc[1][0] = fmaf(xa.y, w.x, acc[1][0]); acc[1][1] = fmaf(xa.y, w.y, acc[1][1]);
            acc[1][2] = fmaf(xa.y, w.z, acc[1][2]); acc[1][3] = fmaf(xa.y, w.w, acc[1][3]);
            acc[2][0] = fmaf(xa.z, w.x, acc[2][0]); acc[2][1] = fmaf(xa.z, w.y, acc[2][1]);
            acc[2][2] = fmaf(xa.z, w.z, acc[2][2]); acc[2][3] = fmaf(xa.z, w.w, acc[2][3]);
            acc[3][0] = fmaf(xa.w, w.x, acc[3][0]); acc[3][1] = fmaf(xa.w, w.y, acc[3][1]);
            acc[3][2] = fmaf(xa.w, w.z, acc[3][2]); acc[3][3] = fmaf(xa.w, w.w, acc[3][3]);
            acc[4][0] = fmaf(xb.x, w.x, acc[4][0]); acc[4][1] = fmaf(xb.x, w.y, acc[4][1]);
            acc[4][2] = fmaf(xb.x, w.z, acc[4][2]); acc[4][3] = fmaf(xb.x, w.w, acc[4][3]);
            acc[5][0] = fmaf(xb.y, w.x, acc[5][0]); acc[5][1] = fmaf(xb.y, w.y, acc[5][1]);
            acc[5][2] = fmaf(xb.y, w.z, acc[5][2]); acc[5][3] = fmaf(xb.y, w.w, acc[5][3]);
            acc[6][0] = fmaf(xb.z, w.x, acc[6][0]); acc[6][1] = fmaf(xb.z, w.y, acc[6][1]);
            acc[6][2] = fmaf(xb.z, w.z, acc[6][2]); acc[6][3] = fmaf(xb.z, w.w, acc[6][3]);
            acc[7][0] = fmaf(xb.w, w.x, acc[7][0]); acc[7][1] = fmaf(xb.w, w.y, acc[7][1]);
            acc[7][2] = fmaf(xb.w, w.z, acc[7][2]); acc[7][3] = fmaf(xb.w, w.w, acc[7][3]);
        }
    }
    // epilogue: scale by dinv[row], pack bf16 pairs, uint2 store per row
#pragma unroll
    for (int r = 0; r < 8; r++) {
        int grr = row0 + ty * 8 + r;
        if (grr < n) {
            float dr = dinv[grr];
            uint2 p;
            p.x = pack_bf16(acc[r][0] * dr, acc[r][1] * dr);
            p.y = pack_bf16(acc[r][2] * dr, acc[r][3] * dr);
            *(uint2*)&hb[(size_t)grr * (D / 2) + tx * 2] = p;
        }
    }
}

// ---------- Aggregation + bias + relu ----------
// hb rows are pre-scaled by dinv[src]; out = relu( dinv[d]*(sum_edges + self) + b ), bf16-packed.
// 1 wave per node; lanes 0-31 gather edge e, lanes 32-63 edge e+1 (uint2 = 4 feats/lane);
// cross-half __shfl_xor(32) reduce at the end.

static __global__ __launch_bounds__(256) void agg_k(const uint2* __restrict__ hb,
                                                    const float* __restrict__ dinv,
                                                    const int* __restrict__ rowptr,
                                                    const int* __restrict__ csr,
                                                    const float* __restrict__ b,
                                                    uint2* __restrict__ outp, int n) {
    int node = blockIdx.x * 4 + (threadIdx.x >> 6);
    if (node >= n) return;
    const int lane = threadIdx.x & 63;
    const int half = lane >> 5;       // which edge of the pair
    const int l32  = lane & 31;       // feature quad: feats 4*l32 .. 4*l32+3
    int beg = rowptr[node], end = rowptr[node + 1];
    float a0 = 0.f, a1 = 0.f, a2 = 0.f, a3 = 0.f;
    int e = beg + half;
    for (; e + 2 < end; e += 4) {     // each half-wave handles 2 edges per iter
        int sA = csr[e], sB = csr[e + 2];
        uint2 vA = hb[(size_t)sA * 32 + l32];
        uint2 vB = hb[(size_t)sB * 32 + l32];
        a0 += bf16_lo(vA.x); a1 += bf16_hi(vA.x);
        a2 += bf16_lo(vA.y); a3 += bf16_hi(vA.y);
        a0 += bf16_lo(vB.x); a1 += bf16_hi(vB.x);
        a2 += bf16_lo(vB.y); a3 += bf16_hi(vB.y);
    }
    if (e < end) {
        int sA = csr[e];
        uint2 vA = hb[(size_t)sA * 32 + l32];
        a0 += bf16_lo(vA.x); a1 += bf16_hi(vA.x);
        a2 += bf16_lo(vA.y); a3 += bf16_hi(vA.y);
    }
    a0 += __shfl_xor(a0, 32);
    a1 += __shfl_xor(a1, 32);
    a2 += __shfl_xor(a2, 32);
    a3 += __shfl_xor(a3, 32);
    uint2 hv = hb[(size_t)node * 32 + l32];     // self loop (pre-scaled by dinv[node])
    a0 += bf16_lo(hv.x); a1 += bf16_hi(hv.x);
    a2 += bf16_lo(hv.y); a3 += bf16_hi(hv.y);
    float di = dinv[node];
    float4 bb = *(const float4*)&b[l32 * 4];
    float o0 = fmaxf(fmaf(di, a0, bb.x), 0.f);
    float o1 = fmaxf(fmaf(di, a1, bb.y), 0.f);
    float o2 = fmaxf(fmaf(di, a2, bb.z), 0.f);
    float o3 = fmaxf(fmaf(di, a3, bb.w), 0.f);
    if (half == 0) {
        uint2 p;
        p.x = pack_bf16(o0, o1);
        p.y = pack_bf16(o2, o3);
        outp[(size_t)node * 32 + l32] = p;
    }
}

// ---------- Global mean pool over packed bf16 (batch is sorted) ----------

static __global__ __launch_bounds__(256) void pool_k(const unsigned int* __restrict__ xp,
                                                     const int* __restrict__ batch, int n,
                                                     float* __restrict__ pooled) {
    int g = blockIdx.x;
    int f = threadIdx.x & 127;
    int half = threadIdx.x >> 7;
    int lo = 0, hi = n;
    while (lo < hi) { int m = (lo + hi) >> 1; if (batch[m] < g) lo = m + 1; else hi = m; }
    int start = lo;
    hi = n;
    while (lo < hi) { int m = (lo + hi) >> 1; if (batch[m] < g + 1) lo = m + 1; else hi = m; }
    int end = lo;
    float s = 0.f;
    const int ui = f >> 1;
    const bool hif = f & 1;
    for (int r = start + half; r < end; r += 2) {
        unsigned int u = xp[(size_t)r * 64 + ui];
        s += hif ? bf16_hi(u) : bf16_lo(u);
    }
    __shared__ float red[256];
    red[threadIdx.x] = s;
    __syncthreads();
    if (half == 0) {
        float tot = red[f] + red[f + 128];
        float c = (float)(end - start);
        pooled[(size_t)g * D + f] = tot / fmaxf(c, 1.0f);
    }
}

// ---------- Classifier: out = relu(pooled@Wc + bc) @ Wo + bo ----------

static __global__ __launch_bounds__(64) void cls_k(const float* __restrict__ pooled,
                                                   const float* __restrict__ Wc,
                                                   const float* __restrict__ bc,
                                                   const float* __restrict__ Wo,
                                                   const float* __restrict__ bo,
                                                   float* __restrict__ out) {
    int g = blockIdx.x;
    int t = threadIdx.x;   // 0..63 -> hidden unit
    __shared__ float p[D];
    p[t] = pooled[(size_t)g * D + t];
    p[t + 64] = pooled[(size_t)g * D + 64 + t];
    __syncthreads();
    float z = bc[t];
    for (int k = 0; k < D; k++) z = fmaf(p[k], Wc[k * H + t], z);
    z = fmaxf(z, 0.f);
    float v = z * Wo[t];
    for (int off = 32; off > 0; off >>= 1) v += __shfl_down(v, off);
    if (t == 0) out[g] = v + bo[0];
}

// ---------- Orchestration ----------

extern "C" void kernel_launch(void* const* d_in, const int* in_sizes, int n_in,
                              void* d_out, int out_size, void* d_ws, size_t ws_size,
                              hipStream_t stream) {
    const float* x     = (const float*)d_in[0];
    const int*   ei    = (const int*)d_in[1];
    const int*   batch = (const int*)d_in[2];
    const float* W1 = (const float*)d_in[3];
    const float* b1 = (const float*)d_in[4];
    const float* W2 = (const float*)d_in[5];
    const float* b2 = (const float*)d_in[6];
    const float* W3 = (const float*)d_in[7];
    const float* b3 = (const float*)d_in[8];
    const float* Wc = (const float*)d_in[9];
    const float* bc = (const float*)d_in[10];
    const float* Wo = (const float*)d_in[11];
    const float* bo = (const float*)d_in[12];

    const int n = in_sizes[0] / D;
    const int E = in_sizes[1] / 2;
    const int G = out_size;

    char* ws = (char*)d_ws;
    size_t off = 0;
    auto alloc = [&](size_t bytes) -> void* {
        void* p = ws + off;
        off = (off + bytes + 255) & ~(size_t)255;
        return p;
    };
    int*   cnt     = (int*)alloc((size_t)n * 4);
    int*   cursor  = (int*)alloc((size_t)n * 4);
    int*   rowptr  = (int*)alloc((size_t)(n + 1) * 4);
    int*   bsum    = (int*)alloc(1024);
    float* dinv    = (float*)alloc((size_t)n * 4);
    int*   csr_src = (int*)alloc((size_t)E * 4);
    unsigned int* hbuf = (unsigned int*)alloc((size_t)n * (D / 2) * 4);  // packed bf16, pre-scaled
    unsigned int* xbuf = (unsigned int*)alloc((size_t)n * (D / 2) * 4);  // packed bf16 layer output
    float* pooled  = (float*)alloc((size_t)G * D * 4);
    (void)ws_size; (void)n_in;

    hipMemsetAsync(cnt, 0, (size_t)n * 4, stream);

    const int TB = 256;
    const int nb = (n + 255) / 256;

    hist_k<<<(E + TB - 1) / TB, TB, 0, stream>>>(ei, E, cnt);
    dinv_k<<<(n + TB - 1) / TB, TB, 0, stream>>>(cnt, dinv, n);
    scanA_k<<<nb, 256, 0, stream>>>(cnt, n, bsum);
    scanB_k<<<1, 64, 0, stream>>>(bsum, nb);
    scanC_k<<<nb, 256, 0, stream>>>(cnt, n, bsum, rowptr);
    cursor_init_k<<<(n + TB - 1) / TB, TB, 0, stream>>>(rowptr, cursor, n);
    fill_k<<<(E + TB - 1) / TB, TB, 0, stream>>>(ei, E, cursor, csr_src);

    const int gemm_blocks = (n + 63) / 64;
    const int agg_blocks  = (n + 3) / 4;

    // layer 1 (fp32 input)
    gemm_k<false><<<gemm_blocks, 256, 0, stream>>>(x, W1, dinv, hbuf, n);
    agg_k<<<agg_blocks, 256, 0, stream>>>((const uint2*)hbuf, dinv, rowptr, csr_src, b1, (uint2*)xbuf, n);
    // layer 2 (packed bf16 input)
    gemm_k<true><<<gemm_blocks, 256, 0, stream>>>(xbuf, W2, dinv, hbuf, n);
    agg_k<<<agg_blocks, 256, 0, stream>>>((const uint2*)hbuf, dinv, rowptr, csr_src, b2, (uint2*)xbuf, n);
    // layer 3
    gemm_k<true><<<gemm_blocks, 256, 0, stream>>>(xbuf, W3, dinv, hbuf, n);
    agg_k<<<agg_blocks, 256, 0, stream>>>((const uint2*)hbuf, dinv, rowptr, csr_src, b3, (uint2*)xbuf, n);

    pool_k<<<G, 256, 0, stream>>>(xbuf, batch, n, pooled);
    cls_k<<<G, 64, 0, stream>>>(pooled, Wc, bc, Wo, bo, (float*)d_out);
}

// Round 5
// 406.573 us; speedup vs baseline: 1.1282x; 1.1282x over previous
//
#include <hip/hip_runtime.h>

#define D 128   // feature dim
#define H 64    // hidden dim of classifier

// ---------- bf16 helpers (bit-level, RNE) ----------

__device__ __forceinline__ unsigned int bf16_rne(float f) {
    unsigned int u = __float_as_uint(f);
    u += 0x7fffu + ((u >> 16) & 1u);
    return u >> 16;
}
__device__ __forceinline__ unsigned int pack_bf16(float a, float b) {
    return bf16_rne(a) | (bf16_rne(b) << 16);
}
__device__ __forceinline__ float bf16_lo(unsigned int u) { return __uint_as_float(u << 16); }
__device__ __forceinline__ float bf16_hi(unsigned int u) { return __uint_as_float(u & 0xffff0000u); }

// ---------- CSR construction ----------
// pass1: one atomic per edge gives within-node rank AND final counts (hist folded in).
// pass2: scatter with no atomics (rank read is coalesced, rowptr gather is L2-resident).

static __global__ void pass1_k(const int* __restrict__ ei, int E,
                               int* __restrict__ cnt, int* __restrict__ rank) {
    int e = blockIdx.x * blockDim.x + threadIdx.x;
    if (e < E) rank[e] = atomicAdd(&cnt[ei[E + e]], 1);
}

static __global__ void dinv_k(const int* __restrict__ cnt, float* __restrict__ dinv, int n) {
    int i = blockIdx.x * blockDim.x + threadIdx.x;
    if (i < n) dinv[i] = rsqrtf((float)cnt[i] + 1.0f);   // +1 self loop; deg >= 1 always
}

static __global__ void scanA_k(const int* __restrict__ cnt, int n, int* __restrict__ bsum) {
    __shared__ int s[256];
    int i = blockIdx.x * 256 + threadIdx.x;
    s[threadIdx.x] = (i < n) ? cnt[i] : 0;
    __syncthreads();
    for (int off = 128; off > 0; off >>= 1) {
        if ((int)threadIdx.x < off) s[threadIdx.x] += s[threadIdx.x + off];
        __syncthreads();
    }
    if (threadIdx.x == 0) bsum[blockIdx.x] = s[0];
}

// parallel exclusive scan of block sums (nb up to a few hundred), one 256-thread block
static __global__ __launch_bounds__(256) void scanB_k(int* __restrict__ bsum, int nb) {
    __shared__ int s[256];
    __shared__ int carry;
    if (threadIdx.x == 0) carry = 0;
    __syncthreads();
    for (int base = 0; base < nb; base += 256) {
        int i = base + threadIdx.x;
        int v = (i < nb) ? bsum[i] : 0;
        s[threadIdx.x] = v;
        __syncthreads();
        for (int off = 1; off < 256; off <<= 1) {   // inclusive Hillis-Steele
            int t = ((int)threadIdx.x >= off) ? s[threadIdx.x - off] : 0;
            __syncthreads();
            s[threadIdx.x] += t;
            __syncthreads();
        }
        if (i < nb) bsum[i] = carry + s[threadIdx.x] - v;   // exclusive
        __syncthreads();
        if (threadIdx.x == 255) carry += s[255];
        __syncthreads();
    }
}

static __global__ void scanC_k(const int* __restrict__ cnt, int n, const int* __restrict__ bsum,
                               int* __restrict__ rowptr) {
    __shared__ int s[256];
    int i = blockIdx.x * 256 + threadIdx.x;
    int v = (i < n) ? cnt[i] : 0;
    s[threadIdx.x] = v;
    __syncthreads();
    for (int off = 1; off < 256; off <<= 1) {       // inclusive Hillis-Steele
        int t = ((int)threadIdx.x >= off) ? s[threadIdx.x - off] : 0;
        __syncthreads();
        s[threadIdx.x] += t;
        __syncthreads();
    }
    if (i < n) {
        int excl = bsum[blockIdx.x] + s[threadIdx.x] - v;
        rowptr[i] = excl;
        if (i == n - 1) rowptr[n] = excl + v;
    }
}

static __global__ void pass2_k(const int* __restrict__ ei, int E,
                               const int* __restrict__ rank,
                               const int* __restrict__ rowptr,
                               int* __restrict__ csr_src) {
    int e = blockIdx.x * blockDim.x + threadIdx.x;
    if (e < E) {
        int d = ei[E + e];
        csr_src[rowptr[d] + rank[e]] = ei[e];   // no atomics; order within node irrelevant
    }
}

// ---------- GEMM: hb = bf16( dinv[row] * (x @ W) ) ----------
// 64-row x 128-col tile, 256 threads, K chunked by 32. LDS 24 KB -> high occupancy.
// PACKED: input x is bf16-packed (agg output); else fp32 (layer-1 input).

template <bool PACKED>
static __global__ __launch_bounds__(256) void gemm_k(const void* __restrict__ xin,
                                                     const float* __restrict__ W,
                                                     const float* __restrict__ dinv,
                                                     unsigned int* __restrict__ hb, int n) {
    __shared__ float Ws[32 * D];     // [kk][col] 16 KB
    __shared__ float xT[32 * 64];    // [kk][row]  8 KB
    const int tid = threadIdx.x;
    const int row0 = blockIdx.x * 64;
    const int tx = tid & 31;        // cols 4*tx .. 4*tx+3
    const int ty = tid >> 5;        // rows 8*ty .. 8*ty+7
    const int sr = tid & 63;        // staging row
    const int sk = (tid >> 6) * 4;  // staging k-offset: 0,4,8,12 (+16 for second quad)
    const int gr = row0 + sr;

    float acc[8][4];
#pragma unroll
    for (int r = 0; r < 8; r++)
#pragma unroll
        for (int c = 0; c < 4; c++) acc[r][c] = 0.f;

    for (int kc = 0; kc < D; kc += 32) {
        float4 wreg[4];
#pragma unroll
        for (int i = 0; i < 4; i++)
            wreg[i] = ((const float4*)(W + kc * D))[tid + 256 * i];
        float4 v0 = make_float4(0.f, 0.f, 0.f, 0.f), v1 = v0;
        if (gr < n) {
            if constexpr (PACKED) {
                const uint2* xp = (const uint2*)xin;
                uint2 u0 = xp[(size_t)gr * 32 + ((kc + sk) >> 2)];
                uint2 u1 = xp[(size_t)gr * 32 + ((kc + sk + 16) >> 2)];
                v0 = make_float4(bf16_lo(u0.x), bf16_hi(u0.x), bf16_lo(u0.y), bf16_hi(u0.y));
                v1 = make_float4(bf16_lo(u1.x), bf16_hi(u1.x), bf16_lo(u1.y), bf16_hi(u1.y));
            } else {
                const float* xf = (const float*)xin;
                v0 = *(const float4*)&xf[(size_t)gr * D + kc + sk];
                v1 = *(const float4*)&xf[(size_t)gr * D + kc + sk + 16];
            }
        }
        __syncthreads();   // previous chunk's compute done
#pragma unroll
        for (int i = 0; i < 4; i++)
            ((float4*)Ws)[tid + 256 * i] = wreg[i];
        xT[(sk + 0) * 64 + sr] = v0.x;
        xT[(sk + 1) * 64 + sr] = v0.y;
        xT[(sk + 2) * 64 + sr] = v0.z;
        xT[(sk + 3) * 64 + sr] = v0.w;
        xT[(sk + 16) * 64 + sr] = v1.x;
        xT[(sk + 17) * 64 + sr] = v1.y;
        xT[(sk + 18) * 64 + sr] = v1.z;
        xT[(sk + 19) * 64 + sr] = v1.w;
        __syncthreads();

#pragma unroll 8
        for (int k = 0; k < 32; k++) {
            float4 w  = *(const float4*)&Ws[k * D + tx * 4];
            float4 xa = *(const float4*)&xT[k * 64 + ty * 8];
            float4 xb = *(const float4*)&xT[k * 64 + ty * 8 + 4];
            acc[0][0] = fmaf(xa.x, w.x, acc[0][0]); acc[0][1] = fmaf(xa.x, w.y, acc[0][1]);
            acc[0][2] = fmaf(xa.x, w.z, acc[0][2]); acc[0][3] = fmaf(xa.x, w.w, acc[0][3]);
            acc[1][0] = fmaf(xa.y, w.x, acc[1][0]); acc[1][1] = fmaf(xa.y, w.y, acc[1][1]);
            acc[1][2] = fmaf(xa.y, w.z, acc[1][2]); acc[1][3] = fmaf(xa.y, w.w, acc[1][3]);
            acc[2][0] = fmaf(xa.z, w.x, acc[2][0]); acc[2][1] = fmaf(xa.z, w.y, acc[2][1]);
            acc[2][2] = fmaf(xa.z, w.z, acc[2][2]); acc[2][3] = fmaf(xa.z, w.w, acc[2][3]);
            acc[3][0] = fmaf(xa.w, w.x, acc[3][0]); acc[3][1] = fmaf(xa.w, w.y, acc[3][1]);
            acc[3][2] = fmaf(xa.w, w.z, acc[3][2]); acc[3][3] = fmaf(xa.w, w.w, acc[3][3]);
            acc[4][0] = fmaf(xb.x, w.x, acc[4][0]); acc[4][1] = fmaf(xb.x, w.y, acc[4][1]);
            acc[4][2] = fmaf(xb.x, w.z, acc[4][2]); acc[4][3] = fmaf(xb.x, w.w, acc[4][3]);
            acc[5][0] = fmaf(xb.y, w.x, acc[5][0]); acc[5][1] = fmaf(xb.y, w.y, acc[5][1]);
            acc[5][2] = fmaf(xb.y, w.z, acc[5][2]); acc[5][3] = fmaf(xb.y, w.w, acc[5][3]);
            acc[6][0] = fmaf(xb.z, w.x, acc[6][0]); acc[6][1] = fmaf(xb.z, w.y, acc[6][1]);
            acc[6][2] = fmaf(xb.z, w.z, acc[6][2]); acc[6][3] = fmaf(xb.z, w.w, acc[6][3]);
            acc[7][0] = fmaf(xb.w, w.x, acc[7][0]); acc[7][1] = fmaf(xb.w, w.y, acc[7][1]);
            acc[7][2] = fmaf(xb.w, w.z, acc[7][2]); acc[7][3] = fmaf(xb.w, w.w, acc[7][3]);
        }
    }
    // epilogue: scale by dinv[row], pack bf16 pairs, uint2 store per row
#pragma unroll
    for (int r = 0; r < 8; r++) {
        int grr = row0 + ty * 8 + r;
        if (grr < n) {
            float dr = dinv[grr];
            uint2 p;
            p.x = pack_bf16(acc[r][0] * dr, acc[r][1] * dr);
            p.y = pack_bf16(acc[r][2] * dr, acc[r][3] * dr);
            *(uint2*)&hb[(size_t)grr * (D / 2) + tx * 2] = p;
        }
    }
}

// ---------- Aggregation + bias + relu ----------
// hb rows pre-scaled by dinv[src]; out = relu( dinv[d]*(sum_edges + self) + b ), bf16-packed.
// 1 wave per node; edge index e is WAVE-UNIFORM (csr loads become scalar s_loads);
// 64 lanes x 1 uint (2 bf16 feats) = 256 B coalesced gather per edge; 4-edge unroll.

static __global__ __launch_bounds__(256) void agg_k(const unsigned int* __restrict__ hb,
                                                    const float* __restrict__ dinv,
                                                    const int* __restrict__ rowptr,
                                                    const int* __restrict__ csr,
                                                    const float* __restrict__ b,
                                                    unsigned int* __restrict__ outp, int n) {
    int node = blockIdx.x * 4 + (threadIdx.x >> 6);
    if (node >= n) return;
    const int lane = threadIdx.x & 63;
    int e = rowptr[node], end = rowptr[node + 1];
    float a0 = 0.f, a1 = 0.f;
    for (; e + 3 < end; e += 4) {
        int s0 = csr[e], s1 = csr[e + 1], s2 = csr[e + 2], s3 = csr[e + 3];
        unsigned int v0 = hb[(size_t)s0 * 64 + lane];
        unsigned int v1 = hb[(size_t)s1 * 64 + lane];
        unsigned int v2 = hb[(size_t)s2 * 64 + lane];
        unsigned int v3 = hb[(size_t)s3 * 64 + lane];
        a0 += bf16_lo(v0); a1 += bf16_hi(v0);
        a0 += bf16_lo(v1); a1 += bf16_hi(v1);
        a0 += bf16_lo(v2); a1 += bf16_hi(v2);
        a0 += bf16_lo(v3); a1 += bf16_hi(v3);
    }
    for (; e < end; e++) {
        int s0 = csr[e];
        unsigned int v0 = hb[(size_t)s0 * 64 + lane];
        a0 += bf16_lo(v0); a1 += bf16_hi(v0);
    }
    unsigned int hv = hb[(size_t)node * 64 + lane];     // self loop (pre-scaled)
    a0 += bf16_lo(hv); a1 += bf16_hi(hv);
    float di = dinv[node];
    float2 bb = *(const float2*)&b[lane * 2];
    float o0 = fmaxf(fmaf(di, a0, bb.x), 0.f);
    float o1 = fmaxf(fmaf(di, a1, bb.y), 0.f);
    outp[(size_t)node * 64 + lane] = pack_bf16(o0, o1);
}

// ---------- Global mean pool over packed bf16 (batch is sorted) ----------

static __global__ __launch_bounds__(256) void pool_k(const unsigned int* __restrict__ xp,
                                                     const int* __restrict__ batch, int n,
                                                     float* __restrict__ pooled) {
    int g = blockIdx.x;
    int f = threadIdx.x & 127;
    int half = threadIdx.x >> 7;
    int lo = 0, hi = n;
    while (lo < hi) { int m = (lo + hi) >> 1; if (batch[m] < g) lo = m + 1; else hi = m; }
    int start = lo;
    hi = n;
    while (lo < hi) { int m = (lo + hi) >> 1; if (batch[m] < g + 1) lo = m + 1; else hi = m; }
    int end = lo;
    float s = 0.f;
    const int ui = f >> 1;
    const bool hif = f & 1;
    for (int r = start + half; r < end; r += 2) {
        unsigned int u = xp[(size_t)r * 64 + ui];
        s += hif ? bf16_hi(u) : bf16_lo(u);
    }
    __shared__ float red[256];
    red[threadIdx.x] = s;
    __syncthreads();
    if (half == 0) {
        float tot = red[f] + red[f + 128];
        float c = (float)(end - start);
        pooled[(size_t)g * D + f] = tot / fmaxf(c, 1.0f);
    }
}

// ---------- Classifier: out = relu(pooled@Wc + bc) @ Wo + bo ----------

static __global__ __launch_bounds__(64) void cls_k(const float* __restrict__ pooled,
                                                   const float* __restrict__ Wc,
                                                   const float* __restrict__ bc,
                                                   const float* __restrict__ Wo,
                                                   const float* __restrict__ bo,
                                                   float* __restrict__ out) {
    int g = blockIdx.x;
    int t = threadIdx.x;   // 0..63 -> hidden unit
    __shared__ float p[D];
    p[t] = pooled[(size_t)g * D + t];
    p[t + 64] = pooled[(size_t)g * D + 64 + t];
    __syncthreads();
    float z = bc[t];
    for (int k = 0; k < D; k++) z = fmaf(p[k], Wc[k * H + t], z);
    z = fmaxf(z, 0.f);
    float v = z * Wo[t];
    for (int off = 32; off > 0; off >>= 1) v += __shfl_down(v, off);
    if (t == 0) out[g] = v + bo[0];
}

// ---------- Orchestration ----------

extern "C" void kernel_launch(void* const* d_in, const int* in_sizes, int n_in,
                              void* d_out, int out_size, void* d_ws, size_t ws_size,
                              hipStream_t stream) {
    const float* x     = (const float*)d_in[0];
    const int*   ei    = (const int*)d_in[1];
    const int*   batch = (const int*)d_in[2];
    const float* W1 = (const float*)d_in[3];
    const float* b1 = (const float*)d_in[4];
    const float* W2 = (const float*)d_in[5];
    const float* b2 = (const float*)d_in[6];
    const float* W3 = (const float*)d_in[7];
    const float* b3 = (const float*)d_in[8];
    const float* Wc = (const float*)d_in[9];
    const float* bc = (const float*)d_in[10];
    const float* Wo = (const float*)d_in[11];
    const float* bo = (const float*)d_in[12];

    const int n = in_sizes[0] / D;
    const int E = in_sizes[1] / 2;
    const int G = out_size;

    char* ws = (char*)d_ws;
    size_t off = 0;
    auto alloc = [&](size_t bytes) -> void* {
        void* p = ws + off;
        off = (off + bytes + 255) & ~(size_t)255;
        return p;
    };
    int*   cnt     = (int*)alloc((size_t)n * 4);
    int*   rowptr  = (int*)alloc((size_t)(n + 1) * 4);
    int*   bsum    = (int*)alloc(1024);
    float* dinv    = (float*)alloc((size_t)n * 4);
    int*   rank    = (int*)alloc((size_t)E * 4);
    int*   csr_src = (int*)alloc((size_t)E * 4);
    unsigned int* hbuf = (unsigned int*)alloc((size_t)n * (D / 2) * 4);  // packed bf16, pre-scaled
    unsigned int* xbuf = (unsigned int*)alloc((size_t)n * (D / 2) * 4);  // packed bf16 layer output
    float* pooled  = (float*)alloc((size_t)G * D * 4);
    (void)ws_size; (void)n_in;

    hipMemsetAsync(cnt, 0, (size_t)n * 4, stream);

    const int TB = 256;
    const int nb = (n + 255) / 256;

    pass1_k<<<(E + TB - 1) / TB, TB, 0, stream>>>(ei, E, cnt, rank);
    dinv_k<<<(n + TB - 1) / TB, TB, 0, stream>>>(cnt, dinv, n);
    scanA_k<<<nb, 256, 0, stream>>>(cnt, n, bsum);
    scanB_k<<<1, 256, 0, stream>>>(bsum, nb);
    scanC_k<<<nb, 256, 0, stream>>>(cnt, n, bsum, rowptr);
    pass2_k<<<(E + TB - 1) / TB, TB, 0, stream>>>(ei, E, rank, rowptr, csr_src);

    const int gemm_blocks = (n + 63) / 64;
    const int agg_blocks  = (n + 3) / 4;

    // layer 1 (fp32 input)
    gemm_k<false><<<gemm_blocks, 256, 0, stream>>>(x, W1, dinv, hbuf, n);
    agg_k<<<agg_blocks, 256, 0, stream>>>(hbuf, dinv, rowptr, csr_src, b1, xbuf, n);
    // layer 2 (packed bf16 input)
    gemm_k<true><<<gemm_blocks, 256, 0, stream>>>(xbuf, W2, dinv, hbuf, n);
    agg_k<<<agg_blocks, 256, 0, stream>>>(hbuf, dinv, rowptr, csr_src, b2, xbuf, n);
    // layer 3
    gemm_k<true><<<gemm_blocks, 256, 0, stream>>>(xbuf, W3, dinv, hbuf, n);
    agg_k<<<agg_blocks, 256, 0, stream>>>(hbuf, dinv, rowptr, csr_src, b3, xbuf, n);

    pool_k<<<G, 256, 0, stream>>>(xbuf, batch, n, pooled);
    cls_k<<<G, 64, 0, stream>>>(pooled, Wc, bc, Wo, bo, (float*)d_out);
}